// Round 12
// baseline (420.500 us; speedup 1.0000x reference)
//
#include <hip/hip_runtime.h>

#define NN 100000
#define NE 1600000
#define NG 512
#define HD 128

#define NBK 196            // node buckets of 512: 196*512 = 100352 >= NN
#define CHUNK 5120         // edges per chunk
#define NC 313             // ceil(NE/CHUNK)
#define LH (2 * NBK * NC)  // 122696 histogram entries (dst part | src part)

typedef _Float16 half4 __attribute__((ext_vector_type(4)));
typedef _Float16 h8 __attribute__((ext_vector_type(8)));
typedef float f32x4 __attribute__((ext_vector_type(4)));

// ---------------- pass A1: per-chunk bucket histograms (dst and src) ----------------
__global__ __launch_bounds__(256) void k_hist(const int* __restrict__ src,
                                              const int* __restrict__ dst,
                                              int* __restrict__ H) {
    __shared__ int hd[NBK], hs[NBK];
    int c = blockIdx.x;
    for (int i = threadIdx.x; i < NBK; i += 256) { hd[i] = 0; hs[i] = 0; }
    __syncthreads();
    int e0 = c * CHUNK;
    int e1 = e0 + CHUNK; if (e1 > NE) e1 = NE;
    for (int e = e0 + threadIdx.x; e < e1; e += 256) {
        atomicAdd(&hd[dst[e] >> 9], 1);
        atomicAdd(&hs[src[e] >> 9], 1);
    }
    __syncthreads();
    for (int i = threadIdx.x; i < NBK; i += 256) {
        H[i * NC + c] = hd[i];
        H[NBK * NC + i * NC + c] = hs[i];
    }
}

// ---------------- generic 3-stage exclusive scan ----------------
__global__ __launch_bounds__(256) void k_scan1g(int* __restrict__ H,
                                                int* __restrict__ bsum, int L) {
    __shared__ int s[256];
    int i = blockIdx.x * 256 + threadIdx.x;
    int v = (i < L) ? H[i] : 0;
    s[threadIdx.x] = v;
    __syncthreads();
    for (int off = 1; off < 256; off <<= 1) {
        int t = (threadIdx.x >= off) ? s[threadIdx.x - off] : 0;
        __syncthreads();
        s[threadIdx.x] += t;
        __syncthreads();
    }
    if (i < L) H[i] = s[threadIdx.x] - v;
    if (threadIdx.x == 255) bsum[blockIdx.x] = s[255];
}

__global__ __launch_bounds__(512) void k_scan2(int* __restrict__ bsum, int nb) {
    __shared__ int s[512];
    int v = (threadIdx.x < nb) ? bsum[threadIdx.x] : 0;
    s[threadIdx.x] = v;
    __syncthreads();
    for (int off = 1; off < 512; off <<= 1) {
        int t = (threadIdx.x >= off) ? s[threadIdx.x - off] : 0;
        __syncthreads();
        s[threadIdx.x] += t;
        __syncthreads();
    }
    if (threadIdx.x < nb) bsum[threadIdx.x] = s[threadIdx.x] - v;
}

__global__ __launch_bounds__(256) void k_scan3g(int* __restrict__ H,
                                                const int* __restrict__ bsum, int L) {
    int i = blockIdx.x * 256 + threadIdx.x;
    if (i < L) H[i] += bsum[i >> 8];
}

// ---------------- pass A2: partition edges into buckets ----------------
// dpart packed: src | (dst&511)<<17  (src < 2^17); spart: src&511 as ushort.
__global__ __launch_bounds__(256) void k_scatter(const int* __restrict__ src,
                                                 const int* __restrict__ dst,
                                                 const int* __restrict__ H,
                                                 int* __restrict__ dpart,
                                                 unsigned short* __restrict__ spart) {
    __shared__ int cd[NBK], cs[NBK];
    int c = blockIdx.x;
    for (int i = threadIdx.x; i < NBK; i += 256) {
        cd[i] = H[i * NC + c];
        cs[i] = H[NBK * NC + i * NC + c] - NE;
    }
    __syncthreads();
    int e0 = c * CHUNK;
    int e1 = e0 + CHUNK; if (e1 > NE) e1 = NE;
    for (int e = e0 + threadIdx.x; e < e1; e += 256) {
        int s = src[e], d = dst[e];
        int pd = atomicAdd(&cd[d >> 9], 1);
        dpart[pd] = s | ((d & 511) << 17);
        int ps = atomicAdd(&cs[s >> 9], 1);
        spart[ps] = (unsigned short)(s & 511);
    }
}

// ---------------- pass B: per-bucket degree count, offs, norms, CSR fill ----------------
__global__ __launch_bounds__(256) void k_bucket(const int* __restrict__ dpart,
                                                const unsigned short* __restrict__ spart,
                                                const int* __restrict__ H,
                                                int* __restrict__ offs,
                                                int* __restrict__ csr,
                                                float* __restrict__ ni,
                                                float* __restrict__ no) {
    __shared__ int deg[512];
    __shared__ int cur[512];
    __shared__ int tmp[256];
    int b = blockIdx.x;
    bool isDst = (b < NBK);
    int bb = isDst ? b : b - NBK;
    int start, end;
    if (isDst) {
        start = H[bb * NC];
        end = (bb + 1 < NBK) ? H[(bb + 1) * NC] : NE;
    } else {
        start = H[NBK * NC + bb * NC] - NE;
        end = (bb + 1 < NBK) ? H[NBK * NC + (bb + 1) * NC] - NE : NE;
    }
    for (int i = threadIdx.x; i < 512; i += 256) deg[i] = 0;
    __syncthreads();
    if (isDst) {
        for (int i = start + threadIdx.x; i < end; i += 256)
            atomicAdd(&deg[(dpart[i] >> 17) & 511], 1);
    } else {
        for (int i = start + threadIdx.x; i < end; i += 256)
            atomicAdd(&deg[spart[i]], 1);
    }
    __syncthreads();
    int vb = bb * 512;
    if (!isDst) {
        for (int i = threadIdx.x; i < 512; i += 256) {
            int v = vb + i;
            if (v < NN) no[v] = rsqrtf(fmaxf((float)deg[i], 1.0f));
        }
        return;
    }
    // exclusive scan of deg[512] with 256 threads
    int t = threadIdx.x;
    int a0 = deg[2 * t], a1 = deg[2 * t + 1];
    int pair = a0 + a1;
    tmp[t] = pair;
    __syncthreads();
    for (int off = 1; off < 256; off <<= 1) {
        int v2 = (t >= off) ? tmp[t - off] : 0;
        __syncthreads();
        tmp[t] += v2;
        __syncthreads();
    }
    int ex = tmp[t] - pair;
    cur[2 * t] = start + ex;
    cur[2 * t + 1] = start + ex + a0;
    __syncthreads();
    for (int i = threadIdx.x; i < 512; i += 256) {
        int v = vb + i;
        if (v < NN) {
            offs[v] = cur[i];
            ni[v] = rsqrtf(fmaxf((float)deg[i], 1.0f));
        }
    }
    if (b == NBK - 1 && threadIdx.x == 0) offs[NN] = NE;
    __syncthreads();
    for (int i = start + threadIdx.x; i < end; i += 256) {
        int pk = dpart[i];
        int p = atomicAdd(&cur[(pk >> 17) & 511], 1);
        csr[p] = pk & 0x1FFFF;
    }
}

// ---------------- W cast+transpose: Bt[w][n][k] = (fp16) W_w[k][n] ----------------
__global__ __launch_bounds__(256) void k_castw(const float* __restrict__ W0,
                                               const float* __restrict__ W1,
                                               const float* __restrict__ W2,
                                               _Float16* __restrict__ Bt) {
    int i = blockIdx.x * 256 + threadIdx.x;  // 3*16384
    if (i >= 3 * 16384) return;
    int w = i >> 14;
    int rem = i & 16383;
    int n = rem >> 7;
    int k = rem & 127;
    const float* W = (w == 0) ? W0 : ((w == 1) ? W1 : W2);
    Bt[i] = (_Float16)W[k * 128 + n];
}

// ---------------- MFMA GEMM: Zh = no[row] * (A @ W), fp16 in, fp32 acc, fp16 out ----
// 391 blocks x 256 rows. B fragments hoisted to registers (loaded once from LDS);
// each wave runs 4 row-tiles of 16 rows: 4 global A-loads + 32 reg-MFMAs per tile.
// Epilogue per tile: wave-private LDS slice (Bs reused), then 16 B coalesced stores.
template <typename TA>
__global__ __launch_bounds__(256) void k_gemm_mfma(const TA* __restrict__ A,
                                                   const _Float16* __restrict__ Bt,
                                                   const float* __restrict__ no,
                                                   _Float16* __restrict__ Zh,
                                                   int nrows) {
    __shared__ _Float16 Bs[128 * 136];  // 34 KB; B staging, then C staging
    int tid = threadIdx.x;
    {
        const h8* B8 = (const h8*)Bt;
        h8* Bs8 = (h8*)Bs;
        for (int i = tid; i < 2048; i += 256) {
            int n = i >> 4, c = i & 15;
            Bs8[n * 17 + c] = B8[i];
        }
    }
    __syncthreads();

    int wave = tid >> 6;
    int lane = tid & 63;
    int m16 = lane & 15;
    int quad = lane >> 4;

    // hoist all B fragments to registers: breg[nt][kk]
    h8 breg[8][4];
    {
        const h8* Bs8 = (const h8*)Bs;
#pragma unroll
        for (int nt = 0; nt < 8; nt++) {
            const h8* Bp = Bs8 + (size_t)(nt * 16 + m16) * 17;
#pragma unroll
            for (int kk = 0; kk < 4; kk++) breg[nt][kk] = Bp[kk * 4 + quad];
        }
    }
    __syncthreads();  // everyone done reading B; LDS free for C staging

#pragma unroll 1
    for (int t = 0; t < 4; t++) {
        int rowbase = blockIdx.x * 256 + t * 64 + wave * 16;
        int row = rowbase + m16;
        bool valid = row < nrows;

        h8 afrag[4];
        if (valid) {
            if constexpr (sizeof(TA) == 2) {
                const h8* Arow = (const h8*)(A + (size_t)row * 128);
#pragma unroll
                for (int kk = 0; kk < 4; kk++) afrag[kk] = Arow[kk * 4 + quad];
            } else {
                const float4* Arow = (const float4*)(A + (size_t)row * 128);
#pragma unroll
                for (int kk = 0; kk < 4; kk++) {
                    float4 lo = Arow[kk * 8 + quad * 2];
                    float4 hi = Arow[kk * 8 + quad * 2 + 1];
                    h8 a;
                    a[0] = (_Float16)lo.x; a[1] = (_Float16)lo.y;
                    a[2] = (_Float16)lo.z; a[3] = (_Float16)lo.w;
                    a[4] = (_Float16)hi.x; a[5] = (_Float16)hi.y;
                    a[6] = (_Float16)hi.z; a[7] = (_Float16)hi.w;
                    afrag[kk] = a;
                }
            }
        } else {
#pragma unroll
            for (int kk = 0; kk < 4; kk++) {
                h8 a;
#pragma unroll
                for (int j = 0; j < 8; j++) a[j] = (_Float16)0.f;
                afrag[kk] = a;
            }
        }

        f32x4 acc[8];
#pragma unroll
        for (int nt = 0; nt < 8; nt++) acc[nt] = (f32x4){0.f, 0.f, 0.f, 0.f};
#pragma unroll
        for (int nt = 0; nt < 8; nt++) {
#pragma unroll
            for (int kk = 0; kk < 4; kk++) {
                acc[nt] = __builtin_amdgcn_mfma_f32_16x16x32_f16(afrag[kk], breg[nt][kk],
                                                                 acc[nt], 0, 0, 0);
            }
        }

        // C/D layout: col = lane&15, row = quad*4 + reg  [m89-verified]
        float nor[4];
#pragma unroll
        for (int r = 0; r < 4; r++) {
            int grow = rowbase + quad * 4 + r;
            nor[r] = (grow < nrows) ? no[grow] : 0.f;
        }
        // stage into wave-private LDS slice (rows wave*16 .. +16), stride 136
        int lr0 = wave * 16 + quad * 4;
#pragma unroll
        for (int nt = 0; nt < 8; nt++) {
#pragma unroll
            for (int r = 0; r < 4; r++) {
                Bs[(size_t)(lr0 + r) * 136 + nt * 16 + m16] =
                    (_Float16)(acc[nt][r] * nor[r]);
            }
        }
        // wave-internal stream-out: 4 rounds x (4 rows x 256 B) coalesced
#pragma unroll
        for (int p2 = 0; p2 < 4; p2++) {
            int r2 = p2 * 4 + (lane >> 4);
            int cch = lane & 15;
            int grow = rowbase + r2;
            if (grow < nrows) {
                h8 val = *(const h8*)&Bs[(size_t)(wave * 16 + r2) * 136 + cch * 8];
                *(h8*)&Zh[(size_t)grow * 128 + cch * 8] = val;
            }
        }
    }
}

// ---------------- aggregation: h'[v] = relu(ni[v]*sum_u zh[u] + b), fp16 out ----------
// 8 nodes per 128-thread block; 16 lanes x h8 (16 B) per node; 4-edge batches.
__global__ __launch_bounds__(128) void k_agg(const h8* __restrict__ Zh,
                                             const int* __restrict__ offs,
                                             const int* __restrict__ csr,
                                             const float* __restrict__ ni,
                                             const float* __restrict__ b,
                                             h8* __restrict__ H16) {
    int v = blockIdx.x * 8 + (threadIdx.x >> 4);
    int c = threadIdx.x & 15;  // 16 col-groups of 8
    int s = offs[v];
    int e = offs[v + 1];
    float a0[8], a1[8];
#pragma unroll
    for (int j = 0; j < 8; j++) { a0[j] = 0.f; a1[j] = 0.f; }
    int i = s;
    for (; i + 4 <= e; i += 4) {
        int u0 = csr[i];
        int u1 = csr[i + 1];
        int u2 = csr[i + 2];
        int u3 = csr[i + 3];
        h8 z0 = Zh[(size_t)u0 * 16 + c];
        h8 z1 = Zh[(size_t)u1 * 16 + c];
        h8 z2 = Zh[(size_t)u2 * 16 + c];
        h8 z3 = Zh[(size_t)u3 * 16 + c];
#pragma unroll
        for (int j = 0; j < 8; j++) {
            a0[j] += (float)z0[j] + (float)z1[j];
            a1[j] += (float)z2[j] + (float)z3[j];
        }
    }
    for (; i < e; i++) {
        int u = csr[i];
        h8 z = Zh[(size_t)u * 16 + c];
#pragma unroll
        for (int j = 0; j < 8; j++) a0[j] += (float)z[j];
    }
    float niv = ni[v];
    const float* bb = b + c * 8;
    h8 r;
#pragma unroll
    for (int j = 0; j < 8; j++)
        r[j] = (_Float16)fmaxf((a0[j] + a1[j]) * niv + bb[j], 0.f);
    H16[(size_t)v * 16 + c] = r;
}

// ---------------- per-graph readout: one block per graph, direct write ----------------
__global__ __launch_bounds__(128) void k_readout(const h8* __restrict__ H8,
                                                 const int* __restrict__ n2g,
                                                 float* __restrict__ g) {
    __shared__ float red[128 * 8];
    int gi = blockIdx.x;
    int t = threadIdx.x;
    int slot = t >> 4;  // 8 node slots
    int c = t & 15;     // feature chunk (8 floats)

    int lo = 0, hi = NN;
    while (lo < hi) { int mid = (lo + hi) >> 1; if (n2g[mid] < gi) lo = mid + 1; else hi = mid; }
    int s = lo;
    hi = NN;
    while (lo < hi) { int mid = (lo + hi) >> 1; if (n2g[mid] < gi + 1) lo = mid + 1; else hi = mid; }
    int e = lo;

    float acc[8];
#pragma unroll
    for (int j = 0; j < 8; j++) acc[j] = 0.f;
    for (int v = s + slot; v < e; v += 8) {
        h8 z = H8[(size_t)v * 16 + c];
#pragma unroll
        for (int j = 0; j < 8; j++) acc[j] += (float)z[j];
    }
#pragma unroll
    for (int j = 0; j < 8; j++) red[t * 8 + j] = acc[j];
    __syncthreads();
    for (int off = 4; off >= 1; off >>= 1) {
        if (slot < off) {
#pragma unroll
            for (int j = 0; j < 8; j++)
                red[t * 8 + j] += red[(t + off * 16) * 8 + j];
        }
        __syncthreads();
    }
    if (slot == 0) {
#pragma unroll
        for (int j = 0; j < 8; j++)
            g[gi * 128 + c * 8 + j] = red[t * 8 + j];
    }
}

// ---------------- MLP head: out = relu(g@Wm1+bm1)@Wm2 + bm2 ----------------
__global__ __launch_bounds__(128) void k_head(const float* __restrict__ g,
                                              const float* __restrict__ Wm1,
                                              const float* __restrict__ bm1,
                                              const float* __restrict__ Wm2,
                                              const float* __restrict__ bm2,
                                              float* __restrict__ out) {
    __shared__ float gs[128];
    __shared__ float red[128];
    int gi = blockIdx.x;
    int f = threadIdx.x;
    gs[f] = g[gi * 128 + f];
    __syncthreads();
    float acc = bm1[f];
    for (int k = 0; k < 128; k++) acc += gs[k] * Wm1[k * 128 + f];
    float h1 = fmaxf(acc, 0.f);
    red[f] = h1 * Wm2[f];
    __syncthreads();
    for (int s2 = 64; s2 > 0; s2 >>= 1) {
        if (f < s2) red[f] += red[f + s2];
        __syncthreads();
    }
    if (f == 0) out[gi] = red[0] + bm2[0];
}

extern "C" void kernel_launch(void* const* d_in, const int* in_sizes, int n_in,
                              void* d_out, int out_size, void* d_ws, size_t ws_size,
                              hipStream_t stream) {
    const float* x   = (const float*)d_in[0];
    const int*   src = (const int*)d_in[1];
    const int*   dst = (const int*)d_in[2];
    const int*   n2g = (const int*)d_in[3];
    const float* W0  = (const float*)d_in[4];
    const float* b0  = (const float*)d_in[5];
    const float* W1  = (const float*)d_in[6];
    const float* b1  = (const float*)d_in[7];
    const float* W2  = (const float*)d_in[8];
    const float* b2  = (const float*)d_in[9];
    const float* Wm1 = (const float*)d_in[10];
    const float* bm1 = (const float*)d_in[11];
    const float* Wm2 = (const float*)d_in[12];
    const float* bm2 = (const float*)d_in[13];
    float* out = (float*)d_out;

    char* p = (char*)d_ws;
    auto carve = [&](size_t bytes) -> char* {
        char* r = p;
        p += (bytes + 255) & ~(size_t)255;
        return r;
    };
    _Float16* zh  = (_Float16*)carve((size_t)NN * HD * 2);
    _Float16* h16 = (_Float16*)carve((size_t)NN * HD * 2);
    _Float16* Bt  = (_Float16*)carve((size_t)3 * 128 * 128 * 2);
    float* no     = (float*)carve((size_t)NN * 4);
    float* ni     = (float*)carve((size_t)NN * 4);
    int*   offs   = (int*)carve((size_t)(NN + 1) * 4);
    int*   csr    = (int*)carve((size_t)NE * 4);
    int*   Hh     = (int*)carve((size_t)LH * 4);
    int*   bsum   = (int*)carve((size_t)512 * 4);
    int*   dpart  = (int*)carve((size_t)NE * 4);
    unsigned short* spart = (unsigned short*)carve((size_t)NE * 2);
    float* g      = (float*)carve((size_t)NG * HD * 4);

    // weight cast+transpose (independent of graph build)
    k_castw<<<(3 * 16384 + 255) / 256, 256, 0, stream>>>(W0, W1, W2, Bt);

    // graph build: bucketed counting sort (LDS atomics, contained writes)
    int scan_blocks = (LH + 255) / 256;  // 480 <= 512
    k_hist<<<NC, 256, 0, stream>>>(src, dst, Hh);
    k_scan1g<<<scan_blocks, 256, 0, stream>>>(Hh, bsum, LH);
    k_scan2<<<1, 512, 0, stream>>>(bsum, scan_blocks);
    k_scan3g<<<scan_blocks, 256, 0, stream>>>(Hh, bsum, LH);
    k_scatter<<<NC, 256, 0, stream>>>(src, dst, Hh, dpart, spart);
    k_bucket<<<2 * NBK, 256, 0, stream>>>(dpart, spart, Hh, offs, csr, ni, no);

    int gemm_blocks = (NN + 255) / 256;  // 391

    // layer 0 (fp32 input, converted in-kernel)
    k_gemm_mfma<float><<<gemm_blocks, 256, 0, stream>>>(x, Bt, no, zh, NN);
    k_agg<<<NN / 8, 128, 0, stream>>>((const h8*)zh, offs, csr, ni, b0, (h8*)h16);
    // layer 1
    k_gemm_mfma<_Float16><<<gemm_blocks, 256, 0, stream>>>(h16, Bt + 16384, no, zh, NN);
    k_agg<<<NN / 8, 128, 0, stream>>>((const h8*)zh, offs, csr, ni, b1, (h8*)h16);
    // layer 2
    k_gemm_mfma<_Float16><<<gemm_blocks, 256, 0, stream>>>(h16, Bt + 32768, no, zh, NN);
    k_agg<<<NN / 8, 128, 0, stream>>>((const h8*)zh, offs, csr, ni, b2, (h8*)h16);

    k_readout<<<NG, 128, 0, stream>>>((const h8*)h16, n2g, g);
    k_head<<<NG, 128, 0, stream>>>(g, Wm1, bm1, Wm2, bm2, out);
}

// Round 13
// 408.219 us; speedup vs baseline: 1.0301x; 1.0301x over previous
//
#include <hip/hip_runtime.h>

#define NN 100000
#define NE 1600000
#define NG 512
#define HD 128

#define NBK 196            // node buckets of 512: 196*512 = 100352 >= NN
#define CHUNK 5120         // edges per chunk
#define NC 313             // ceil(NE/CHUNK)
#define LH (2 * NBK * NC)  // 122696 histogram entries (dst part | src part)

typedef _Float16 half4 __attribute__((ext_vector_type(4)));
typedef _Float16 h8 __attribute__((ext_vector_type(8)));
typedef float f32x4 __attribute__((ext_vector_type(4)));

// ---------------- pass A1: per-chunk bucket histograms + fused weight cast ----------
// blocks [0, NC): histogram chunks; blocks [NC, NC+192): cast W0..W2 -> Bt (fp16, transposed)
__global__ __launch_bounds__(256) void k_hist(const int* __restrict__ src,
                                              const int* __restrict__ dst,
                                              int* __restrict__ H,
                                              const float* __restrict__ W0,
                                              const float* __restrict__ W1,
                                              const float* __restrict__ W2,
                                              _Float16* __restrict__ Bt) {
    if (blockIdx.x >= NC) {
        int i = (blockIdx.x - NC) * 256 + threadIdx.x;  // < 3*16384
        int w = i >> 14;
        int rem = i & 16383;
        int n = rem >> 7;
        int k = rem & 127;
        const float* W = (w == 0) ? W0 : ((w == 1) ? W1 : W2);
        Bt[i] = (_Float16)W[k * 128 + n];
        return;
    }
    __shared__ int hd[NBK], hs[NBK];
    int c = blockIdx.x;
    for (int i = threadIdx.x; i < NBK; i += 256) { hd[i] = 0; hs[i] = 0; }
    __syncthreads();
    int e0 = c * CHUNK;
    int e1 = e0 + CHUNK; if (e1 > NE) e1 = NE;
    for (int e = e0 + threadIdx.x; e < e1; e += 256) {
        atomicAdd(&hd[dst[e] >> 9], 1);
        atomicAdd(&hs[src[e] >> 9], 1);
    }
    __syncthreads();
    for (int i = threadIdx.x; i < NBK; i += 256) {
        H[i * NC + c] = hd[i];
        H[NBK * NC + i * NC + c] = hs[i];
    }
}

// ---------------- scan stage 1: per-256-block exclusive scan + block sums ----------------
__global__ __launch_bounds__(256) void k_scan1g(int* __restrict__ H,
                                                int* __restrict__ bsum, int L) {
    __shared__ int s[256];
    int i = blockIdx.x * 256 + threadIdx.x;
    int v = (i < L) ? H[i] : 0;
    s[threadIdx.x] = v;
    __syncthreads();
    for (int off = 1; off < 256; off <<= 1) {
        int t = (threadIdx.x >= off) ? s[threadIdx.x - off] : 0;
        __syncthreads();
        s[threadIdx.x] += t;
        __syncthreads();
    }
    if (i < L) H[i] = s[threadIdx.x] - v;
    if (threadIdx.x == 255) bsum[blockIdx.x] = s[255];
}

// ---------------- scan stage 2 (fused): every block re-scans bsum in LDS, then adds ----
__global__ __launch_bounds__(256) void k_scan3g(int* __restrict__ H,
                                                const int* __restrict__ bsum,
                                                int L, int nb) {
    __shared__ int sb[512];
    __shared__ int tmp2[256];
    int t = threadIdx.x;
    int b0 = (2 * t < nb) ? bsum[2 * t] : 0;
    int b1 = (2 * t + 1 < nb) ? bsum[2 * t + 1] : 0;
    int pair = b0 + b1;
    tmp2[t] = pair;
    __syncthreads();
    for (int off = 1; off < 256; off <<= 1) {
        int v2 = (t >= off) ? tmp2[t - off] : 0;
        __syncthreads();
        tmp2[t] += v2;
        __syncthreads();
    }
    int ex = tmp2[t] - pair;
    sb[2 * t] = ex;
    sb[2 * t + 1] = ex + b0;
    __syncthreads();
    int i = blockIdx.x * 256 + t;
    if (i < L) H[i] += sb[i >> 8];
}

// ---------------- pass A2: partition edges into buckets ----------------
// dpart packed: src | (dst&511)<<17  (src < 2^17); spart: src&511 as ushort.
__global__ __launch_bounds__(256) void k_scatter(const int* __restrict__ src,
                                                 const int* __restrict__ dst,
                                                 const int* __restrict__ H,
                                                 int* __restrict__ dpart,
                                                 unsigned short* __restrict__ spart) {
    __shared__ int cd[NBK], cs[NBK];
    int c = blockIdx.x;
    for (int i = threadIdx.x; i < NBK; i += 256) {
        cd[i] = H[i * NC + c];
        cs[i] = H[NBK * NC + i * NC + c] - NE;
    }
    __syncthreads();
    int e0 = c * CHUNK;
    int e1 = e0 + CHUNK; if (e1 > NE) e1 = NE;
    for (int e = e0 + threadIdx.x; e < e1; e += 256) {
        int s = src[e], d = dst[e];
        int pd = atomicAdd(&cd[d >> 9], 1);
        dpart[pd] = s | ((d & 511) << 17);
        int ps = atomicAdd(&cs[s >> 9], 1);
        spart[ps] = (unsigned short)(s & 511);
    }
}

// ---------------- pass B: per-bucket degree count, offs, norms, CSR fill ----------------
__global__ __launch_bounds__(256) void k_bucket(const int* __restrict__ dpart,
                                                const unsigned short* __restrict__ spart,
                                                const int* __restrict__ H,
                                                int* __restrict__ offs,
                                                int* __restrict__ csr,
                                                float* __restrict__ ni,
                                                float* __restrict__ no) {
    __shared__ int deg[512];
    __shared__ int cur[512];
    __shared__ int tmp[256];
    int b = blockIdx.x;
    bool isDst = (b < NBK);
    int bb = isDst ? b : b - NBK;
    int start, end;
    if (isDst) {
        start = H[bb * NC];
        end = (bb + 1 < NBK) ? H[(bb + 1) * NC] : NE;
    } else {
        start = H[NBK * NC + bb * NC] - NE;
        end = (bb + 1 < NBK) ? H[NBK * NC + (bb + 1) * NC] - NE : NE;
    }
    for (int i = threadIdx.x; i < 512; i += 256) deg[i] = 0;
    __syncthreads();
    if (isDst) {
        for (int i = start + threadIdx.x; i < end; i += 256)
            atomicAdd(&deg[(dpart[i] >> 17) & 511], 1);
    } else {
        for (int i = start + threadIdx.x; i < end; i += 256)
            atomicAdd(&deg[spart[i]], 1);
    }
    __syncthreads();
    int vb = bb * 512;
    if (!isDst) {
        for (int i = threadIdx.x; i < 512; i += 256) {
            int v = vb + i;
            if (v < NN) no[v] = rsqrtf(fmaxf((float)deg[i], 1.0f));
        }
        return;
    }
    // exclusive scan of deg[512] with 256 threads
    int t = threadIdx.x;
    int a0 = deg[2 * t], a1 = deg[2 * t + 1];
    int pair = a0 + a1;
    tmp[t] = pair;
    __syncthreads();
    for (int off = 1; off < 256; off <<= 1) {
        int v2 = (t >= off) ? tmp[t - off] : 0;
        __syncthreads();
        tmp[t] += v2;
        __syncthreads();
    }
    int ex = tmp[t] - pair;
    cur[2 * t] = start + ex;
    cur[2 * t + 1] = start + ex + a0;
    __syncthreads();
    for (int i = threadIdx.x; i < 512; i += 256) {
        int v = vb + i;
        if (v < NN) {
            offs[v] = cur[i];
            ni[v] = rsqrtf(fmaxf((float)deg[i], 1.0f));
        }
    }
    if (b == NBK - 1 && threadIdx.x == 0) offs[NN] = NE;
    __syncthreads();
    for (int i = start + threadIdx.x; i < end; i += 256) {
        int pk = dpart[i];
        int p = atomicAdd(&cur[(pk >> 17) & 511], 1);
        csr[p] = pk & 0x1FFFF;
    }
}

// ---------------- MFMA GEMM: Zh = no[row] * (A @ W), fp16 in, fp32 acc, fp16 out ----
// R11 structure (equal-best): 64 rows/block, LDS-staged B (+8-half pad), LDS-staged
// coalesced h8 epilogue (direct 2 B stores were the bottleneck — fixed in R11).
template <typename TA>
__global__ __launch_bounds__(256) void k_gemm_mfma(const TA* __restrict__ A,
                                                   const _Float16* __restrict__ Bt,
                                                   const float* __restrict__ no,
                                                   _Float16* __restrict__ Zh,
                                                   int nrows) {
    __shared__ _Float16 Bs[128 * 136];  // 34 KB; B staging, then C staging
    int tid = threadIdx.x;
    {
        const h8* B8 = (const h8*)Bt;
        h8* Bs8 = (h8*)Bs;
        for (int i = tid; i < 2048; i += 256) {
            int n = i >> 4, c = i & 15;
            Bs8[n * 17 + c] = B8[i];
        }
    }

    int wave = tid >> 6;
    int lane = tid & 63;
    int m16 = lane & 15;
    int quad = lane >> 4;
    int rowbase = blockIdx.x * 64 + wave * 16;
    int row = rowbase + m16;
    bool valid = row < nrows;

    h8 afrag[4];
    if (valid) {
        if constexpr (sizeof(TA) == 2) {
            const h8* Arow = (const h8*)(A + (size_t)row * 128);
#pragma unroll
            for (int kk = 0; kk < 4; kk++) afrag[kk] = Arow[kk * 4 + quad];
        } else {
            const float4* Arow = (const float4*)(A + (size_t)row * 128);
#pragma unroll
            for (int kk = 0; kk < 4; kk++) {
                float4 lo = Arow[kk * 8 + quad * 2];
                float4 hi = Arow[kk * 8 + quad * 2 + 1];
                h8 a;
                a[0] = (_Float16)lo.x; a[1] = (_Float16)lo.y;
                a[2] = (_Float16)lo.z; a[3] = (_Float16)lo.w;
                a[4] = (_Float16)hi.x; a[5] = (_Float16)hi.y;
                a[6] = (_Float16)hi.z; a[7] = (_Float16)hi.w;
                afrag[kk] = a;
            }
        }
    } else {
#pragma unroll
        for (int kk = 0; kk < 4; kk++) {
            h8 a;
#pragma unroll
            for (int j = 0; j < 8; j++) a[j] = (_Float16)0.f;
            afrag[kk] = a;
        }
    }

    __syncthreads();

    f32x4 acc[8];
#pragma unroll
    for (int nt = 0; nt < 8; nt++) acc[nt] = (f32x4){0.f, 0.f, 0.f, 0.f};

    const h8* Bs8 = (const h8*)Bs;
#pragma unroll
    for (int nt = 0; nt < 8; nt++) {
        const h8* Bp = Bs8 + (size_t)(nt * 16 + m16) * 17;
#pragma unroll
        for (int kk = 0; kk < 4; kk++) {
            acc[nt] = __builtin_amdgcn_mfma_f32_16x16x32_f16(afrag[kk], Bp[kk * 4 + quad],
                                                             acc[nt], 0, 0, 0);
        }
    }

    // C/D layout: col = lane&15, row = quad*4 + reg  [m89-verified]
    float nor[4];
#pragma unroll
    for (int r = 0; r < 4; r++) {
        int grow = rowbase + quad * 4 + r;
        nor[r] = (grow < nrows) ? no[grow] : 0.f;
    }

    __syncthreads();  // all waves done reading Bs; reuse as C staging
    {
        int lr0 = wave * 16 + quad * 4;
#pragma unroll
        for (int nt = 0; nt < 8; nt++) {
#pragma unroll
            for (int r = 0; r < 4; r++) {
                Bs[(size_t)(lr0 + r) * 136 + nt * 16 + m16] =
                    (_Float16)(acc[nt][r] * nor[r]);
            }
        }
    }
    __syncthreads();

    int blockrow0 = blockIdx.x * 64;
    for (int i = tid; i < 1024; i += 256) {
        int r = i >> 4, cch = i & 15;
        int grow = blockrow0 + r;
        if (grow < nrows) {
            h8 val = *(const h8*)&Bs[(size_t)r * 136 + cch * 8];
            *(h8*)&Zh[(size_t)grow * 128 + cch * 8] = val;
        }
    }
}

// ---------------- aggregation: h'[v] = relu(ni[v]*sum_u zh[u] + b), fp16 out ----------
// 16 nodes per 256-thread block; 16 lanes x h8 (16 B) per node; 4-edge batches.
__global__ __launch_bounds__(256) void k_agg(const h8* __restrict__ Zh,
                                             const int* __restrict__ offs,
                                             const int* __restrict__ csr,
                                             const float* __restrict__ ni,
                                             const float* __restrict__ b,
                                             h8* __restrict__ H16) {
    int v = blockIdx.x * 16 + (threadIdx.x >> 4);
    int c = threadIdx.x & 15;  // 16 col-groups of 8
    int s = offs[v];
    int e = offs[v + 1];
    float a0[8], a1[8];
#pragma unroll
    for (int j = 0; j < 8; j++) { a0[j] = 0.f; a1[j] = 0.f; }
    int i = s;
    for (; i + 4 <= e; i += 4) {
        int u0 = csr[i];
        int u1 = csr[i + 1];
        int u2 = csr[i + 2];
        int u3 = csr[i + 3];
        h8 z0 = Zh[(size_t)u0 * 16 + c];
        h8 z1 = Zh[(size_t)u1 * 16 + c];
        h8 z2 = Zh[(size_t)u2 * 16 + c];
        h8 z3 = Zh[(size_t)u3 * 16 + c];
#pragma unroll
        for (int j = 0; j < 8; j++) {
            a0[j] += (float)z0[j] + (float)z1[j];
            a1[j] += (float)z2[j] + (float)z3[j];
        }
    }
    for (; i < e; i++) {
        int u = csr[i];
        h8 z = Zh[(size_t)u * 16 + c];
#pragma unroll
        for (int j = 0; j < 8; j++) a0[j] += (float)z[j];
    }
    float niv = ni[v];
    const float* bb = b + c * 8;
    h8 r;
#pragma unroll
    for (int j = 0; j < 8; j++)
        r[j] = (_Float16)fmaxf((a0[j] + a1[j]) * niv + bb[j], 0.f);
    H16[(size_t)v * 16 + c] = r;
}

// ---------------- fused readout + MLP head: one block per graph ----------------
// readout: binary-search node range, 8 node-slots x 16 feature-chunks, LDS reduce.
// head: g row stays in LDS; out[gi] = relu(g@Wm1+bm1)@Wm2 + bm2.
__global__ __launch_bounds__(128) void k_readhead(const h8* __restrict__ H8,
                                                  const int* __restrict__ n2g,
                                                  const float* __restrict__ Wm1,
                                                  const float* __restrict__ bm1,
                                                  const float* __restrict__ Wm2,
                                                  const float* __restrict__ bm2,
                                                  float* __restrict__ out) {
    __shared__ float red[128 * 8];
    __shared__ float gs[128];
    __shared__ float red2[128];
    int gi = blockIdx.x;
    int t = threadIdx.x;
    int slot = t >> 4;  // 8 node slots
    int c = t & 15;     // feature chunk (8 floats)

    int lo = 0, hi = NN;
    while (lo < hi) { int mid = (lo + hi) >> 1; if (n2g[mid] < gi) lo = mid + 1; else hi = mid; }
    int s = lo;
    hi = NN;
    while (lo < hi) { int mid = (lo + hi) >> 1; if (n2g[mid] < gi + 1) lo = mid + 1; else hi = mid; }
    int e = lo;

    float acc[8];
#pragma unroll
    for (int j = 0; j < 8; j++) acc[j] = 0.f;
    for (int v = s + slot; v < e; v += 8) {
        h8 z = H8[(size_t)v * 16 + c];
#pragma unroll
        for (int j = 0; j < 8; j++) acc[j] += (float)z[j];
    }
#pragma unroll
    for (int j = 0; j < 8; j++) red[t * 8 + j] = acc[j];
    __syncthreads();
    for (int off = 4; off >= 1; off >>= 1) {
        if (slot < off) {
#pragma unroll
            for (int j = 0; j < 8; j++)
                red[t * 8 + j] += red[(t + off * 16) * 8 + j];
        }
        __syncthreads();
    }
    if (slot == 0) {
#pragma unroll
        for (int j = 0; j < 8; j++) gs[c * 8 + j] = red[t * 8 + j];
    }
    __syncthreads();

    // head
    int f = t;
    float a = bm1[f];
    for (int k = 0; k < 128; k++) a += gs[k] * Wm1[k * 128 + f];
    float h1 = fmaxf(a, 0.f);
    red2[f] = h1 * Wm2[f];
    __syncthreads();
    for (int s2 = 64; s2 > 0; s2 >>= 1) {
        if (f < s2) red2[f] += red2[f + s2];
        __syncthreads();
    }
    if (f == 0) out[gi] = red2[0] + bm2[0];
}

extern "C" void kernel_launch(void* const* d_in, const int* in_sizes, int n_in,
                              void* d_out, int out_size, void* d_ws, size_t ws_size,
                              hipStream_t stream) {
    const float* x   = (const float*)d_in[0];
    const int*   src = (const int*)d_in[1];
    const int*   dst = (const int*)d_in[2];
    const int*   n2g = (const int*)d_in[3];
    const float* W0  = (const float*)d_in[4];
    const float* b0  = (const float*)d_in[5];
    const float* W1  = (const float*)d_in[6];
    const float* b1  = (const float*)d_in[7];
    const float* W2  = (const float*)d_in[8];
    const float* b2  = (const float*)d_in[9];
    const float* Wm1 = (const float*)d_in[10];
    const float* bm1 = (const float*)d_in[11];
    const float* Wm2 = (const float*)d_in[12];
    const float* bm2 = (const float*)d_in[13];
    float* out = (float*)d_out;

    char* p = (char*)d_ws;
    auto carve = [&](size_t bytes) -> char* {
        char* r = p;
        p += (bytes + 255) & ~(size_t)255;
        return r;
    };
    _Float16* zh  = (_Float16*)carve((size_t)NN * HD * 2);
    _Float16* h16 = (_Float16*)carve((size_t)NN * HD * 2);
    _Float16* Bt  = (_Float16*)carve((size_t)3 * 128 * 128 * 2);
    float* no     = (float*)carve((size_t)NN * 4);
    float* ni     = (float*)carve((size_t)NN * 4);
    int*   offs   = (int*)carve((size_t)(NN + 1) * 4);
    int*   csr    = (int*)carve((size_t)NE * 4);
    int*   Hh     = (int*)carve((size_t)LH * 4);
    int*   bsum   = (int*)carve((size_t)512 * 4);
    int*   dpart  = (int*)carve((size_t)NE * 4);
    unsigned short* spart = (unsigned short*)carve((size_t)NE * 2);

    // graph build (castw fused into hist as extra blocks)
    int scan_blocks = (LH + 255) / 256;  // 480 <= 512
    k_hist<<<NC + 192, 256, 0, stream>>>(src, dst, Hh, W0, W1, W2, Bt);
    k_scan1g<<<scan_blocks, 256, 0, stream>>>(Hh, bsum, LH);
    k_scan3g<<<scan_blocks, 256, 0, stream>>>(Hh, bsum, LH, scan_blocks);
    k_scatter<<<NC, 256, 0, stream>>>(src, dst, Hh, dpart, spart);
    k_bucket<<<2 * NBK, 256, 0, stream>>>(dpart, spart, Hh, offs, csr, ni, no);

    int gemm_blocks = (NN + 63) / 64;  // 1563
    int agg_blocks  = NN / 16;         // 6250

    // layer 0 (fp32 input, converted in-kernel)
    k_gemm_mfma<float><<<gemm_blocks, 256, 0, stream>>>(x, Bt, no, zh, NN);
    k_agg<<<agg_blocks, 256, 0, stream>>>((const h8*)zh, offs, csr, ni, b0, (h8*)h16);
    // layer 1
    k_gemm_mfma<_Float16><<<gemm_blocks, 256, 0, stream>>>(h16, Bt + 16384, no, zh, NN);
    k_agg<<<agg_blocks, 256, 0, stream>>>((const h8*)zh, offs, csr, ni, b1, (h8*)h16);
    // layer 2
    k_gemm_mfma<_Float16><<<gemm_blocks, 256, 0, stream>>>(h16, Bt + 32768, no, zh, NN);
    k_agg<<<agg_blocks, 256, 0, stream>>>((const h8*)zh, offs, csr, ni, b2, (h8*)h16);

    k_readhead<<<NG, 128, 0, stream>>>((const h8*)h16, n2g, Wm1, bm1, Wm2, bm2, out);
}